// Round 19
// baseline (1059.912 us; speedup 1.0000x reference)
//
#include <hip/hip_runtime.h>
#include <math.h>

#define TWO_PI 6.283185307179586f

// HARNESS MODEL (verified R8-R18): d_out = 33,362,176 f32 = Re(out), [bc][l][m].
// Math: xr[c][k][m] = (2pi/720) * sum_n x[c][k][n] * cos(2pi n m/720)
//       out[c][l][m] = sum_k xr[c][k][m] * W[m][l][k]
// R19: LDS-free barrier-free s1 (R18 structure) with accuracy fixes:
//  - A tail values for n>360 explicitly zeroed (bit-identical to R17's staging;
//    R18 fed junk x[361..383] and failed at 6.7e-4 vs 6.5e-4 threshold)
//  - RNE hi/lo splits (not truncation) + full 4-product MFMA (adds al*bl):
//    split representation error ~2^-18 rel, mathematically closer to f32.
// s2/transpose unchanged (proven).

typedef __attribute__((ext_vector_type(8))) short bf16x8;
typedef __attribute__((ext_vector_type(4))) float f32x4;

union BFU { uint4 u; bf16x8 v; };

__device__ inline unsigned short f2bf(float f) {
    union { float f; unsigned int u; } v; v.f = f;
    unsigned int u = v.u;
    return (unsigned short)((u + 0x7fffu + ((u >> 16) & 1u)) >> 16);  // RNE
}
__device__ inline float bf2f(unsigned short h) {
    union { unsigned int u; float f; } v; v.u = ((unsigned int)h) << 16;
    return v.f;
}
__device__ inline unsigned int packhl(float v) {
    unsigned short h = f2bf(v);
    unsigned short l = f2bf(v - bf2f(h));
    return (unsigned int)h | ((unsigned int)l << 16);
}
__device__ inline void split2(float a, float b, unsigned int& hh, unsigned int& ll) {
    unsigned short ha = f2bf(a), hb = f2bf(b);
    unsigned short la = f2bf(a - bf2f(ha)), lb = f2bf(b - bf2f(hb));
    hh = (unsigned int)ha | ((unsigned int)hb << 16);
    ll = (unsigned int)la | ((unsigned int)lb << 16);
}
// bijective chunked XCD swizzle (m204)
__device__ inline int xcd_work(int bid, int nwg) {
    int q = nwg >> 3, r = nwg & 7;
    int xcd = bid & 7, ord = bid >> 3;
    return (xcd < r ? xcd * (q + 1) : r * (q + 1) + (xcd - r) * q) + ord;
}

// ---------------- tables: EcT_hi/lo [384][384] bf16, EcT[m][n] = sigma*cos, n<=360 ----------------
__global__ void build_ect(unsigned short* __restrict__ Eh,
                          unsigned short* __restrict__ El) {
    const float sigma = TWO_PI / 720.0f;
    const int total = 384 * 384;
    for (int i = blockIdx.x * blockDim.x + threadIdx.x; i < total;
         i += gridDim.x * blockDim.x) {
        int m = i / 384, n = i % 384;
        float v = 0.f;
        if (m < 361 && n <= 360) {
            int r = (n * m) % 720;  // exact phase reduction
            v = sigma * cosf((float)r * (TWO_PI / 720.0f));
        }
        unsigned short h = f2bf(v);
        Eh[i] = h;
        El[i] = f2bf(v - bf2f(h));
    }
}

// ---------------- stage 1: xr[m][q] = sum_{n<=360} y[q][n]*EcT[m][n] ----------------
// y[n] = x[n]+x[720-n] (n=1..359), y0=x0, y360=x360, y(n>360)=0.
// 256 thr = 4 waves; tile 64q x 96m; NO LDS, NO BARRIERS; K=384 (12 iters).
__global__ __launch_bounds__(256, 4) void s1_mfma(
    const float* __restrict__ x, const unsigned short* __restrict__ Eh,
    const unsigned short* __restrict__ El, unsigned int* __restrict__ xrp,
    const int Q) {
    const int work = xcd_work(blockIdx.x, gridDim.x);
    const int q0 = (work >> 2) * 64;
    const int m0g = (work & 3) * 96;
    const int t = threadIdx.x;
    const int lane = t & 63, wv = t >> 6;
    const int lr = lane & 15, lk = lane >> 4;

    const int aq = q0 + wv * 16 + lr;          // this lane's A row
    const float* arow = x + (size_t)aq * 720;
    const bool qv = (aq < Q);

    // B fragment bases: row m0g+lr, col lk*8 (+16*384 per nj, +32 per it)
    const unsigned short* brow_h = Eh + (size_t)(m0g + lr) * 384 + lk * 8;
    const unsigned short* brow_l = El + (size_t)(m0g + lr) * 384 + lk * 8;

    f32x4 acc[6];
#pragma unroll
    for (int nj = 0; nj < 6; ++nj)
#pragma unroll
        for (int r = 0; r < 4; ++r) acc[nj][r] = 0.f;

    for (int it = 0; it < 12; ++it) {
        const int n0 = it * 32 + lk * 8;
        // ---- A fragment: fold + split, fully in registers ----
        float y[8];
        if (qv) {
            float4 fa = *(const float4*)(arow + n0);
            float4 fb = *(const float4*)(arow + n0 + 4);
            float f[8] = {fa.x, fa.y, fa.z, fa.w, fb.x, fb.y, fb.z, fb.w};
#pragma unroll
            for (int j = 0; j < 8; ++j) {
                int n = n0 + j;
                float v = (n <= 360) ? f[j] : 0.f;   // zero the tail (R18 fix)
                if (n >= 1 && n < 360) v += arow[720 - n];
                y[j] = v;
            }
        } else {
#pragma unroll
            for (int j = 0; j < 8; ++j) y[j] = 0.f;
        }
        BFU ahu, alu;
        split2(y[0], y[1], ahu.u.x, alu.u.x);
        split2(y[2], y[3], ahu.u.y, alu.u.y);
        split2(y[4], y[5], ahu.u.z, alu.u.z);
        split2(y[6], y[7], ahu.u.w, alu.u.w);
        const bf16x8 ah = ahu.v, al = alu.v;

        // ---- B fragments direct from tables; 4 products per nj ----
#pragma unroll
        for (int nj = 0; nj < 6; ++nj) {
            bf16x8 bh = *(const bf16x8*)(brow_h + (size_t)nj * (16 * 384) + it * 32);
            bf16x8 bl = *(const bf16x8*)(brow_l + (size_t)nj * (16 * 384) + it * 32);
            acc[nj] = __builtin_amdgcn_mfma_f32_16x16x32_bf16(ah, bh, acc[nj], 0, 0, 0);
            acc[nj] = __builtin_amdgcn_mfma_f32_16x16x32_bf16(ah, bl, acc[nj], 0, 0, 0);
            acc[nj] = __builtin_amdgcn_mfma_f32_16x16x32_bf16(al, bh, acc[nj], 0, 0, 0);
            acc[nj] = __builtin_amdgcn_mfma_f32_16x16x32_bf16(al, bl, acc[nj], 0, 0, 0);
        }
    }

    // epilogue: D col = m (m0g+nj*16+lr), row = q (q0+wv*16+lk*4+reg)
#pragma unroll
    for (int nj = 0; nj < 6; ++nj) {
        int m = m0g + nj * 16 + lr;
        if (m >= 361) continue;
        size_t base = (size_t)m * Q;
#pragma unroll
        for (int reg = 0; reg < 4; ++reg) {
            int q = q0 + wv * 16 + lk * 4 + reg;
            if (q < Q) xrp[base + q] = packhl(acc[nj][reg]);
        }
    }
}

// ---------------- stage 2: per-m GEMM, tile 128bc x 64l (R14 proven form) ----------------
__global__ __launch_bounds__(256, 4) void s2_mfma(
    const unsigned int* __restrict__ xrp, const float* __restrict__ W,
    float* __restrict__ stg, const int CH) {
    __shared__ short Ah[128][40], Al[128][40];   // 10 KB each
    __shared__ short Bh[64][40], Bl[64][40];     // 5 KB each -> 30 KB

    const int work = xcd_work(blockIdx.x, gridDim.x);
    const int m = work / 12;
    const int rem = work % 12;
    const int half = rem / 6, lt = rem % 6;
    const int l0 = lt * 64;
    if (l0 + 63 < m) return;          // dead tile: zero-filled by transpose
    const int bcbase = half * 128;
    if (bcbase >= CH) return;
    const int Q = CH * 361;
    const int t = threadIdx.x;
    const int lane = t & 63, wv = t >> 6;
    const int lr = lane & 15, lk = lane >> 4;
    const int wbc = wv >> 1, wl = wv & 1;

    const unsigned int* Am = xrp + (size_t)m * Q;
    const float* Wm = W + (size_t)m * 130321;

    f32x4 acc[4][2];
#pragma unroll
    for (int fi = 0; fi < 4; ++fi)
#pragma unroll
        for (int ni = 0; ni < 2; ++ni)
#pragma unroll
            for (int r = 0; r < 4; ++r) acc[fi][ni][r] = 0.f;

    unsigned int pa0[8], pa1[8];
    float wva[4], wvb[4];

#define S2_LOADR(K0)                                                          \
    {                                                                         \
        _Pragma("unroll") for (int i = 0; i < 8; ++i) {                       \
            int id = t + i * 256;                                             \
            int r = id >> 4, kp = id & 15;                                    \
            int bc = bcbase + r, kg = (K0) + kp * 2;                          \
            unsigned int p0 = 0, p1 = 0;                                      \
            if (bc < CH) {                                                    \
                size_t base = (size_t)bc * 361;                               \
                if (kg < 361) p0 = Am[base + kg];                             \
                if (kg + 1 < 361) p1 = Am[base + kg + 1];                     \
            }                                                                 \
            pa0[i] = p0; pa1[i] = p1;                                         \
        }                                                                     \
        _Pragma("unroll") for (int i = 0; i < 4; ++i) {                       \
            int id = t + i * 256;                                             \
            int r = id >> 4, kp = id & 15;                                    \
            int l = l0 + r, kg = (K0) + kp * 2;                               \
            float va = 0.f, vb = 0.f;                                         \
            if (l < 361) {                                                    \
                size_t base = (size_t)l * 361;                                \
                if (kg < 361) va = Wm[base + kg];                             \
                if (kg + 1 < 361) vb = Wm[base + kg + 1];                     \
            }                                                                 \
            wva[i] = va; wvb[i] = vb;                                         \
        }                                                                     \
    }
#define S2_WRITES()                                                           \
    {                                                                         \
        _Pragma("unroll") for (int i = 0; i < 8; ++i) {                       \
            int id = t + i * 256;                                             \
            int r = id >> 4, kp = id & 15;                                    \
            *(unsigned int*)&Ah[r][kp * 2] =                                  \
                (pa0[i] & 0xffffu) | (pa1[i] << 16);                          \
            *(unsigned int*)&Al[r][kp * 2] =                                  \
                (pa0[i] >> 16) | (pa1[i] & 0xffff0000u);                      \
        }                                                                     \
        _Pragma("unroll") for (int i = 0; i < 4; ++i) {                       \
            int id = t + i * 256;                                             \
            int r = id >> 4, kp = id & 15;                                    \
            unsigned int hh, ll;                                              \
            split2(wva[i], wvb[i], hh, ll);                                   \
            *(unsigned int*)&Bh[r][kp * 2] = hh;                              \
            *(unsigned int*)&Bl[r][kp * 2] = ll;                              \
        }                                                                     \
    }

    S2_LOADR(0);
    S2_WRITES();
    __syncthreads();
    for (int it = 0; it < 12; ++it) {
        if (it + 1 < 12) S2_LOADR((it + 1) * 32);
#pragma unroll
        for (int fi = 0; fi < 4; ++fi) {
            bf16x8 ah = *(const bf16x8*)&Ah[wbc * 64 + fi * 16 + lr][lk * 8];
            bf16x8 al = *(const bf16x8*)&Al[wbc * 64 + fi * 16 + lr][lk * 8];
#pragma unroll
            for (int ni = 0; ni < 2; ++ni) {
                bf16x8 bh = *(const bf16x8*)&Bh[wl * 32 + ni * 16 + lr][lk * 8];
                bf16x8 bl = *(const bf16x8*)&Bl[wl * 32 + ni * 16 + lr][lk * 8];
                acc[fi][ni] = __builtin_amdgcn_mfma_f32_16x16x32_bf16(ah, bh, acc[fi][ni], 0, 0, 0);
                acc[fi][ni] = __builtin_amdgcn_mfma_f32_16x16x32_bf16(ah, bl, acc[fi][ni], 0, 0, 0);
                acc[fi][ni] = __builtin_amdgcn_mfma_f32_16x16x32_bf16(al, bh, acc[fi][ni], 0, 0, 0);
            }
        }
        __syncthreads();
        if (it + 1 < 12) {
            S2_WRITES();
            __syncthreads();
        }
    }

    // epilogue: stg[(m*CH+bc)*361+l]
#pragma unroll
    for (int fi = 0; fi < 4; ++fi) {
#pragma unroll
        for (int ni = 0; ni < 2; ++ni) {
            int l = l0 + wl * 32 + ni * 16 + lr;
#pragma unroll
            for (int reg = 0; reg < 4; ++reg) {
                int bc = bcbase + wbc * 64 + fi * 16 + lk * 4 + reg;
                if (bc < CH && l < 361)
                    stg[((size_t)m * CH + bc) * 361 + l] = acc[fi][ni][reg];
            }
        }
    }
}

// ---------------- transpose stg [m][q'] -> out, zero-filling dead tiles ----------------
__global__ __launch_bounds__(256) void transpose_out(const float* __restrict__ stg,
                                                     float* __restrict__ out,
                                                     const int c0, const int CH) {
    __shared__ float tile[32][33];
    const int Q = CH * 361;
    const int m0 = blockIdx.y * 32, q0 = blockIdx.x * 32;
    const int tx = threadIdx.x & 31, ty = threadIdx.x >> 5;
    for (int i = ty; i < 32; i += 8) {
        int mm = m0 + i, q = q0 + tx;
        float v = 0.f;
        if (mm < 361 && q < Q) {
            int l = q % 361;
            if ((l | 63) >= mm) v = stg[(size_t)mm * Q + q];  // live 64-tile
        }
        tile[i][tx] = v;
    }
    __syncthreads();
    for (int i = ty; i < 32; i += 8) {
        int q = q0 + i, mm = m0 + tx;
        if (mm < 361 && q < Q)
            out[((size_t)c0 * 361 + q) * 361 + mm] = tile[tx][i];
    }
}

extern "C" void kernel_launch(void* const* d_in, const int* in_sizes, int n_in,
                              void* d_out, int out_size, void* d_ws, size_t ws_size,
                              hipStream_t stream) {
    (void)out_size;
    // select inputs by element count: x = 66,539,520; W = 47,045,881
    const float* x = (const float*)d_in[0];
    const float* W = (const float*)d_in[1];
    if (n_in >= 2 && (in_sizes[0] == 47045881 || in_sizes[1] == 66539520)) {
        x = (const float*)d_in[1];
        W = (const float*)d_in[0];
    }
    float* out = (float*)d_out;

    // ws layout (bytes): EcT_hi [384][384] | EcT_lo | xrp (uint) | stg (f32)
    const size_t offEh = 0;
    const size_t offEl = 294912;                 // 384*384*2
    const size_t offData = 589824;

    const int cands[6] = {256, 128, 64, 32, 16, 8};
    int CH = 0;
    for (int i = 0; i < 6; ++i) {
        size_t need = offData + 2ull * cands[i] * 130321ull * 4ull;
        if (need <= ws_size) { CH = cands[i]; break; }
    }
    if (!CH) return;  // workspace too small: fail visibly, don't fault

    unsigned short* Eh = (unsigned short*)((char*)d_ws + offEh);
    unsigned short* El = (unsigned short*)((char*)d_ws + offEl);
    unsigned int* xrp = (unsigned int*)((char*)d_ws + offData);
    float* stg = (float*)((char*)d_ws + offData + (size_t)CH * 130321ull * 4ull);

    build_ect<<<256, 256, 0, stream>>>(Eh, El);

    const int Q = CH * 361;
    const int qt = (Q + 63) / 64;
    for (int c0 = 0; c0 < 256; c0 += CH) {
        s1_mfma<<<qt * 4, 256, 0, stream>>>(
            x + (size_t)c0 * 361 * 720, Eh, El, xrp, Q);
        s2_mfma<<<361 * 12, 256, 0, stream>>>(xrp, W, stg, CH);
        transpose_out<<<dim3((Q + 31) / 32, 12), 256, 0, stream>>>(stg, out, c0, CH);
    }
}

// Round 20
// 600.334 us; speedup vs baseline: 1.7655x; 1.7655x over previous
//
#include <hip/hip_runtime.h>
#include <math.h>

#define TWO_PI 6.283185307179586f

// HARNESS MODEL (verified R8-R19): d_out = 33,362,176 f32 = Re(out), [bc][l][m].
// Math: xr[c][k][m] = (2pi/720) * sum_n x[c][k][n] * cos(2pi n m/720)
//       out[c][l][m] = sum_k xr[c][k][m] * W[m][l][k]
// R20: s1 = R17's proven staged pipeline, with the B-copy switched to
// global_load_lds (width 16) issued at the TOP of each iteration — the
// L2->reg->LDS round trip was on the serial path between MFMA and barrier.
// B LDS layout verified: thread id's dest offset = id*16 (lane-linear). A
// (fold+split) keeps R17's scalar reg-prefetch. s2/transpose unchanged.

typedef __attribute__((ext_vector_type(8))) short bf16x8;
typedef __attribute__((ext_vector_type(4))) float f32x4;

__device__ inline unsigned short f2bf(float f) {
    union { float f; unsigned int u; } v; v.f = f;
    unsigned int u = v.u;
    return (unsigned short)((u + 0x7fffu + ((u >> 16) & 1u)) >> 16);  // RNE
}
__device__ inline float bf2f(unsigned short h) {
    union { unsigned int u; float f; } v; v.u = ((unsigned int)h) << 16;
    return v.f;
}
__device__ inline unsigned int packhl(float v) {
    unsigned short h = f2bf(v);
    unsigned short l = f2bf(v - bf2f(h));
    return (unsigned int)h | ((unsigned int)l << 16);
}
__device__ inline void split2(float a, float b, unsigned int& hh, unsigned int& ll) {
    unsigned short ha = f2bf(a), hb = f2bf(b);
    unsigned short la = f2bf(a - bf2f(ha)), lb = f2bf(b - bf2f(hb));
    hh = (unsigned int)ha | ((unsigned int)hb << 16);
    ll = (unsigned int)la | ((unsigned int)lb << 16);
}
// truncation split: v = hi + (v-hi), residual exact (~2^-16 rel) — R17-proven
__device__ inline void split2t(float a, float b, unsigned int& hh, unsigned int& ll) {
    union { float f; unsigned int u; } ua, ub, fa, fb, la, lb;
    ua.f = a; ub.f = b;
    hh = (ua.u >> 16) | (ub.u & 0xffff0000u);
    fa.u = ua.u & 0xffff0000u;
    fb.u = ub.u & 0xffff0000u;
    la.f = a - fa.f;
    lb.f = b - fb.f;
    ll = (la.u >> 16) | (lb.u & 0xffff0000u);
}
// async global->LDS, 16B per lane; LDS dest must be wave-uniform base + lane*16
__device__ inline void gload_lds16(const void* g, void* l) {
    __builtin_amdgcn_global_load_lds(
        (const __attribute__((address_space(1))) unsigned int*)g,
        (__attribute__((address_space(3))) unsigned int*)l, 16, 0, 0);
}
// bijective chunked XCD swizzle (m204)
__device__ inline int xcd_work(int bid, int nwg) {
    int q = nwg >> 3, r = nwg & 7;
    int xcd = bid & 7, ord = bid >> 3;
    return (xcd < r ? xcd * (q + 1) : r * (q + 1) + (xcd - r) * q) + ord;
}

// ---------------- tables: EcT_hi/lo [384][384] bf16, EcT[m][n] = sigma*cos, n<=360 ----------------
__global__ void build_ect(unsigned short* __restrict__ Eh,
                          unsigned short* __restrict__ El) {
    const float sigma = TWO_PI / 720.0f;
    const int total = 384 * 384;
    for (int i = blockIdx.x * blockDim.x + threadIdx.x; i < total;
         i += gridDim.x * blockDim.x) {
        int m = i / 384, n = i % 384;
        float v = 0.f;
        if (m < 361 && n <= 360) {
            int r = (n * m) % 720;  // exact phase reduction
            v = sigma * cosf((float)r * (TWO_PI / 720.0f));
        }
        unsigned short h = f2bf(v);
        Eh[i] = h;
        El[i] = f2bf(v - bf2f(h));
    }
}

// ---------------- stage 1: xr[m][q] = sum_{n<=360} y[q][n]*EcT[m][n] ----------------
// y[n] = x[n]+x[720-n] (n=1..359), y0=x0, y360=x360.  12 iters, dbuf,
// 1 barrier/iter; B staged via global_load_lds issued before the MFMA phase.
__global__ __launch_bounds__(256, 4) void s1_mfma(
    const float* __restrict__ x, const unsigned short* __restrict__ Eh,
    const unsigned short* __restrict__ El, unsigned int* __restrict__ xrp,
    const int Q) {
    __shared__ short Ah[2][4][64][8], Al[2][4][64][8];   // 16 KB
    __shared__ short Bt[2][2][4][96][8];                 // 24.5 KB -> 40 KB total

    const int work = xcd_work(blockIdx.x, gridDim.x);
    const int q0 = (work >> 2) * 64;
    const int m0g = (work & 3) * 96;
    const int t = threadIdx.x;
    const int lane = t & 63, wv = t >> 6;
    const int lr = lane & 15, lk = lane >> 4;
    const int wq = wv;

    const int ar = t >> 2, akc = t & 3;
    const int aq = q0 + ar;
    const float* arow = x + (size_t)aq * 720;
    const bool aqv = (aq < Q);

    // B copy geometry: thread id (t + i*256) sources table row m0g+r, cols
    // kc*8..kc*8+7 and lands at LDS byte offset id*16 within buffer NB
    // (verified lane-linear: dest = wave-uniform base + lane*16).
    const unsigned short* bsrc[3];
#pragma unroll
    for (int i = 0; i < 3; ++i) {
        int id = t + i * 256;
        int tab = id / 384, rem = id % 384;
        int kc = rem / 96, r = rem % 96;
        bsrc[i] = (tab ? El : Eh) + (size_t)(m0g + r) * 384 + kc * 8;
    }

    f32x4 acc[6];
#pragma unroll
    for (int nj = 0; nj < 6; ++nj)
#pragma unroll
        for (int r = 0; r < 4; ++r) acc[nj][r] = 0.f;

    float4 f0a, f0b, pra, prb;   // A raw prefetch; fold+split in WRITEA

#define S1_LOADA(K0)                                                       \
    {                                                                      \
        int kg = (K0) + akc * 8;                                           \
        f0a = make_float4(0.f, 0.f, 0.f, 0.f);                             \
        f0b = f0a; pra = f0a; prb = f0a;                                   \
        if (aqv) {                                                         \
            if (kg <= 352) {                                               \
                f0a = *(const float4*)(arow + kg);                         \
                f0b = *(const float4*)(arow + kg + 4);                     \
            } else if (kg == 360) {                                        \
                f0a.x = arow[360];                                         \
            }                                                              \
            if (kg >= 8 && kg <= 352) {                                    \
                pra = *(const float4*)(arow + 713 - kg);                   \
                prb = *(const float4*)(arow + 717 - kg);                   \
            } else if (kg == 0) {                                          \
                float tm[8];                                               \
                _Pragma("unroll") for (int i = 0; i < 8; ++i) {            \
                    int n = 7 - i;                                         \
                    tm[i] = (n >= 1) ? arow[713 + i] : 0.f;                \
                }                                                          \
                pra = make_float4(tm[0], tm[1], tm[2], tm[3]);             \
                prb = make_float4(tm[4], tm[5], tm[6], tm[7]);             \
            }                                                              \
        }                                                                  \
    }
#define S1_WRITEA(NB)                                                     \
    {                                                                     \
        float y0 = f0a.x + prb.w, y1 = f0a.y + prb.z;                     \
        float y2 = f0a.z + prb.y, y3 = f0a.w + prb.x;                     \
        float y4 = f0b.x + pra.w, y5 = f0b.y + pra.z;                     \
        float y6 = f0b.z + pra.y, y7 = f0b.w + pra.x;                     \
        unsigned int h0, h1, h2, h3, l0, l1, l2, l3;                      \
        split2t(y0, y1, h0, l0);                                          \
        split2t(y2, y3, h1, l1);                                          \
        split2t(y4, y5, h2, l2);                                          \
        split2t(y6, y7, h3, l3);                                          \
        *(uint4*)&Ah[NB][akc][ar][0] = make_uint4(h0, h1, h2, h3);        \
        *(uint4*)&Al[NB][akc][ar][0] = make_uint4(l0, l1, l2, l3);        \
    }
    // async B copy: 3 x 16B DMA per thread into buffer NB at byte id*16
#define S1_COPYB(NB, K0)                                                  \
    {                                                                     \
        char* bb = (char*)&Bt[NB][0][0][0][0];                            \
        _Pragma("unroll") for (int i = 0; i < 3; ++i) {                   \
            gload_lds16(bsrc[i] + (K0), bb + (t + i * 256) * 16);         \
        }                                                                 \
    }

    S1_COPYB(0, 0);
    S1_LOADA(0);
    S1_WRITEA(0);
    __syncthreads();   // drains vmcnt (DMA) + lgkm (ds_write)
    int cur = 0;
    const int NIT = 12;   // K = 368 padded to 384
    for (int it = 0; it < NIT; ++it) {
        const int nb = cur ^ 1;
        if (it + 1 < NIT) {
            S1_COPYB(nb, (it + 1) * 32);   // DMA proceeds during MFMA phase
            S1_LOADA((it + 1) * 32);       // A HBM latency hidden under MFMA
        }
        bf16x8 ah = *(const bf16x8*)&Ah[cur][lk][wq * 16 + lr][0];
        bf16x8 al = *(const bf16x8*)&Al[cur][lk][wq * 16 + lr][0];
#pragma unroll
        for (int nj = 0; nj < 6; ++nj) {
            bf16x8 bh = *(const bf16x8*)&Bt[cur][0][lk][nj * 16 + lr][0];
            bf16x8 bl = *(const bf16x8*)&Bt[cur][1][lk][nj * 16 + lr][0];
            acc[nj] = __builtin_amdgcn_mfma_f32_16x16x32_bf16(ah, bh, acc[nj], 0, 0, 0);
            acc[nj] = __builtin_amdgcn_mfma_f32_16x16x32_bf16(ah, bl, acc[nj], 0, 0, 0);
            acc[nj] = __builtin_amdgcn_mfma_f32_16x16x32_bf16(al, bh, acc[nj], 0, 0, 0);
        }
        if (it + 1 < NIT) {
            S1_WRITEA(nb);
            __syncthreads();
            cur = nb;
        }
    }

    // epilogue: D col=m, row=q (verified mapping)
#pragma unroll
    for (int nj = 0; nj < 6; ++nj) {
        int m = m0g + nj * 16 + lr;
        if (m >= 361) continue;
        size_t base = (size_t)m * Q;
#pragma unroll
        for (int reg = 0; reg < 4; ++reg) {
            int q = q0 + wq * 16 + lk * 4 + reg;
            if (q < Q) xrp[base + q] = packhl(acc[nj][reg]);
        }
    }
}

// ---------------- stage 2: per-m GEMM, tile 128bc x 64l (R14 proven form) ----------------
__global__ __launch_bounds__(256, 4) void s2_mfma(
    const unsigned int* __restrict__ xrp, const float* __restrict__ W,
    float* __restrict__ stg, const int CH) {
    __shared__ short Ah[128][40], Al[128][40];   // 10 KB each
    __shared__ short Bh[64][40], Bl[64][40];     // 5 KB each -> 30 KB

    const int work = xcd_work(blockIdx.x, gridDim.x);
    const int m = work / 12;
    const int rem = work % 12;
    const int half = rem / 6, lt = rem % 6;
    const int l0 = lt * 64;
    if (l0 + 63 < m) return;          // dead tile: zero-filled by transpose
    const int bcbase = half * 128;
    if (bcbase >= CH) return;
    const int Q = CH * 361;
    const int t = threadIdx.x;
    const int lane = t & 63, wv = t >> 6;
    const int lr = lane & 15, lk = lane >> 4;
    const int wbc = wv >> 1, wl = wv & 1;

    const unsigned int* Am = xrp + (size_t)m * Q;
    const float* Wm = W + (size_t)m * 130321;

    f32x4 acc[4][2];
#pragma unroll
    for (int fi = 0; fi < 4; ++fi)
#pragma unroll
        for (int ni = 0; ni < 2; ++ni)
#pragma unroll
            for (int r = 0; r < 4; ++r) acc[fi][ni][r] = 0.f;

    unsigned int pa0[8], pa1[8];
    float wva[4], wvb[4];

#define S2_LOADR(K0)                                                          \
    {                                                                         \
        _Pragma("unroll") for (int i = 0; i < 8; ++i) {                       \
            int id = t + i * 256;                                             \
            int r = id >> 4, kp = id & 15;                                    \
            int bc = bcbase + r, kg = (K0) + kp * 2;                          \
            unsigned int p0 = 0, p1 = 0;                                      \
            if (bc < CH) {                                                    \
                size_t base = (size_t)bc * 361;                               \
                if (kg < 361) p0 = Am[base + kg];                             \
                if (kg + 1 < 361) p1 = Am[base + kg + 1];                     \
            }                                                                 \
            pa0[i] = p0; pa1[i] = p1;                                         \
        }                                                                     \
        _Pragma("unroll") for (int i = 0; i < 4; ++i) {                       \
            int id = t + i * 256;                                             \
            int r = id >> 4, kp = id & 15;                                    \
            int l = l0 + r, kg = (K0) + kp * 2;                               \
            float va = 0.f, vb = 0.f;                                         \
            if (l < 361) {                                                    \
                size_t base = (size_t)l * 361;                                \
                if (kg < 361) va = Wm[base + kg];                             \
                if (kg + 1 < 361) vb = Wm[base + kg + 1];                     \
            }                                                                 \
            wva[i] = va; wvb[i] = vb;                                         \
        }                                                                     \
    }
#define S2_WRITES()                                                           \
    {                                                                         \
        _Pragma("unroll") for (int i = 0; i < 8; ++i) {                       \
            int id = t + i * 256;                                             \
            int r = id >> 4, kp = id & 15;                                    \
            *(unsigned int*)&Ah[r][kp * 2] =                                  \
                (pa0[i] & 0xffffu) | (pa1[i] << 16);                          \
            *(unsigned int*)&Al[r][kp * 2] =                                  \
                (pa0[i] >> 16) | (pa1[i] & 0xffff0000u);                      \
        }                                                                     \
        _Pragma("unroll") for (int i = 0; i < 4; ++i) {                       \
            int id = t + i * 256;                                             \
            int r = id >> 4, kp = id & 15;                                    \
            unsigned int hh, ll;                                              \
            split2(wva[i], wvb[i], hh, ll);                                   \
            *(unsigned int*)&Bh[r][kp * 2] = hh;                              \
            *(unsigned int*)&Bl[r][kp * 2] = ll;                              \
        }                                                                     \
    }

    S2_LOADR(0);
    S2_WRITES();
    __syncthreads();
    for (int it = 0; it < 12; ++it) {
        if (it + 1 < 12) S2_LOADR((it + 1) * 32);
#pragma unroll
        for (int fi = 0; fi < 4; ++fi) {
            bf16x8 ah = *(const bf16x8*)&Ah[wbc * 64 + fi * 16 + lr][lk * 8];
            bf16x8 al = *(const bf16x8*)&Al[wbc * 64 + fi * 16 + lr][lk * 8];
#pragma unroll
            for (int ni = 0; ni < 2; ++ni) {
                bf16x8 bh = *(const bf16x8*)&Bh[wl * 32 + ni * 16 + lr][lk * 8];
                bf16x8 bl = *(const bf16x8*)&Bl[wl * 32 + ni * 16 + lr][lk * 8];
                acc[fi][ni] = __builtin_amdgcn_mfma_f32_16x16x32_bf16(ah, bh, acc[fi][ni], 0, 0, 0);
                acc[fi][ni] = __builtin_amdgcn_mfma_f32_16x16x32_bf16(ah, bl, acc[fi][ni], 0, 0, 0);
                acc[fi][ni] = __builtin_amdgcn_mfma_f32_16x16x32_bf16(al, bh, acc[fi][ni], 0, 0, 0);
            }
        }
        __syncthreads();
        if (it + 1 < 12) {
            S2_WRITES();
            __syncthreads();
        }
    }

    // epilogue: stg[(m*CH+bc)*361+l]
#pragma unroll
    for (int fi = 0; fi < 4; ++fi) {
#pragma unroll
        for (int ni = 0; ni < 2; ++ni) {
            int l = l0 + wl * 32 + ni * 16 + lr;
#pragma unroll
            for (int reg = 0; reg < 4; ++reg) {
                int bc = bcbase + wbc * 64 + fi * 16 + lk * 4 + reg;
                if (bc < CH && l < 361)
                    stg[((size_t)m * CH + bc) * 361 + l] = acc[fi][ni][reg];
            }
        }
    }
}

// ---------------- transpose stg [m][q'] -> out, zero-filling dead tiles ----------------
__global__ __launch_bounds__(256) void transpose_out(const float* __restrict__ stg,
                                                     float* __restrict__ out,
                                                     const int c0, const int CH) {
    __shared__ float tile[32][33];
    const int Q = CH * 361;
    const int m0 = blockIdx.y * 32, q0 = blockIdx.x * 32;
    const int tx = threadIdx.x & 31, ty = threadIdx.x >> 5;
    for (int i = ty; i < 32; i += 8) {
        int mm = m0 + i, q = q0 + tx;
        float v = 0.f;
        if (mm < 361 && q < Q) {
            int l = q % 361;
            if ((l | 63) >= mm) v = stg[(size_t)mm * Q + q];  // live 64-tile
        }
        tile[i][tx] = v;
    }
    __syncthreads();
    for (int i = ty; i < 32; i += 8) {
        int q = q0 + i, mm = m0 + tx;
        if (mm < 361 && q < Q)
            out[((size_t)c0 * 361 + q) * 361 + mm] = tile[tx][i];
    }
}

extern "C" void kernel_launch(void* const* d_in, const int* in_sizes, int n_in,
                              void* d_out, int out_size, void* d_ws, size_t ws_size,
                              hipStream_t stream) {
    (void)out_size;
    // select inputs by element count: x = 66,539,520; W = 47,045,881
    const float* x = (const float*)d_in[0];
    const float* W = (const float*)d_in[1];
    if (n_in >= 2 && (in_sizes[0] == 47045881 || in_sizes[1] == 66539520)) {
        x = (const float*)d_in[1];
        W = (const float*)d_in[0];
    }
    float* out = (float*)d_out;

    // ws layout (bytes): EcT_hi [384][384] | EcT_lo | xrp (uint) | stg (f32)
    const size_t offEh = 0;
    const size_t offEl = 294912;                 // 384*384*2
    const size_t offData = 589824;

    const int cands[6] = {256, 128, 64, 32, 16, 8};
    int CH = 0;
    for (int i = 0; i < 6; ++i) {
        size_t need = offData + 2ull * cands[i] * 130321ull * 4ull;
        if (need <= ws_size) { CH = cands[i]; break; }
    }
    if (!CH) return;  // workspace too small: fail visibly, don't fault

    unsigned short* Eh = (unsigned short*)((char*)d_ws + offEh);
    unsigned short* El = (unsigned short*)((char*)d_ws + offEl);
    unsigned int* xrp = (unsigned int*)((char*)d_ws + offData);
    float* stg = (float*)((char*)d_ws + offData + (size_t)CH * 130321ull * 4ull);

    build_ect<<<256, 256, 0, stream>>>(Eh, El);

    const int Q = CH * 361;
    const int qt = (Q + 63) / 64;
    for (int c0 = 0; c0 < 256; c0 += CH) {
        s1_mfma<<<qt * 4, 256, 0, stream>>>(
            x + (size_t)c0 * 361 * 720, Eh, El, xrp, Q);
        s2_mfma<<<361 * 12, 256, 0, stream>>>(xrp, W, stg, CH);
        transpose_out<<<dim3((Q + 31) / 32, 12), 256, 0, stream>>>(stg, out, c0, CH);
    }
}